// Round 4
// baseline (429.784 us; speedup 1.0000x reference)
//
#include <hip/hip_runtime.h>
#include <hip/hip_fp16.h>

#define HID 50
#define LAT 16
#define NW  4          // waves per block (independent after one-time dt staging)
#define BLK (NW * 64)
#define MPW 32         // TWO MFMA M-tiles per wave (R4: intra-wave ILP)

typedef __attribute__((ext_vector_type(8))) _Float16 half8v;  // 8 f16 = 4 VGPRs
typedef __attribute__((ext_vector_type(4))) float f32x4;
typedef __attribute__((ext_vector_type(2))) float f32x2;
typedef __attribute__((ext_vector_type(4))) unsigned uint4v;

#define MFMAH(a, b, c) __builtin_amdgcn_mfma_f32_16x16x32_f16(a, b, c, 0, 0, 0)

// pack two fp32 -> dword of 2 f16 (v_cvt_pkrtz_f16_f32, 1 instr)
__device__ __forceinline__ unsigned pkhf(float lo, float hi) {
    __half2 h = __float22half2_rn(float2{lo, hi});
    unsigned r;
    __builtin_memcpy(&r, &h, 4);
    return r;
}

// kappa-label -> hidden-unit map (R15 repack).  Tiles 0-2 hold real units
// 0..47; tile 3 holds units 48,49 at m=0,1 (q=0), the bias/sat slot at
// kappa==38 (m=2, q=0), everything else dead.
__device__ __forceinline__ int unitmap(int k, bool& dead, bool& sat) {
    dead = false; sat = false;
    int u = k;
    if (k == 36)                          u = 48;
    else if (k == 37)                     u = 49;
    else if (k == 38)                     sat = true;
    else if (k == 39)                     dead = true;
    else if (k >= 44 && k < 48)           dead = true;
    else if ((k >= 48 && k < 52) || (k >= 56 && k < 60)) u = k - 12;
    else if (k >= 52 && k < 56)           dead = true;
    else if (k >= 60)                     dead = true;
    return u;   // k<36 (not 36-39) and 40-43: identity
}

// ---- A-frag builders (weights as f16 MFMA A-operand; one-time setup) ----
__device__ __forceinline__ half8v afrag1(const float* __restrict__ W, const float* __restrict__ bias,
                                         int Kreal, int ti, int q, int m, float scale) {
    int kap = 32 * (ti >> 1) + 8 * (m >> 2) + 4 * (ti & 1) + (m & 3);
    bool dead, sat;
    int u = unitmap(kap, dead, sat);
    float e[8];
#pragma unroll
    for (int j = 0; j < 8; j++) {
        float f = 0.0f;
        if (!dead && !sat) {
            if (j < 4) {
                int row = 4 * q + j;
                if (row < Kreal) f = W[row * HID + u] * scale;
            } else if (j == 4 && q == 0) f = bias[u] * scale;
        }
        e[j] = f;
    }
    uint4v d;
#pragma unroll
    for (int p = 0; p < 4; p++) d[p] = pkhf(e[2 * p], e[2 * p + 1]);
    return __builtin_bit_cast(half8v, d);
}

__device__ __forceinline__ half8v afrag2(const float* __restrict__ W2, const float* __restrict__ b2,
                                         int N2, int chunk, int q, int m) {
    float e[8];
#pragma unroll
    for (int j = 0; j < 8; j++) {
        int kap = 32 * chunk + 8 * q + j;
        bool dead, sat;
        int u = unitmap(kap, dead, sat);
        float f = 0.0f;
        if (m < N2) {
            if (sat)       f = b2[m];
            else if (!dead) f = W2[u * N2 + m];
        }
        e[j] = f;
    }
    uint4v d;
#pragma unroll
    for (int p = 0; p < 4; p++) d[p] = pkhf(e[2 * p], e[2 * p + 1]);
    return __builtin_bit_cast(half8v, d);
}

__global__ void __attribute__((amdgpu_flat_work_group_size(BLK, BLK), amdgpu_waves_per_eu(2, 2)))
node_kernel(const float* __restrict__ x0, const float* __restrict__ tt,
            const float* __restrict__ We1, const float* __restrict__ be1,
            const float* __restrict__ We2, const float* __restrict__ be2,
            const float* __restrict__ Wo1, const float* __restrict__ bo1,
            const float* __restrict__ Wo2, const float* __restrict__ bo2,
            const float* __restrict__ Wd1, const float* __restrict__ bd1,
            const float* __restrict__ Wd2, const float* __restrict__ bd2,
            float* __restrict__ out, int B, int T) {
    __shared__ float sdt[128];   // dt table (lgkm-side; loop stays vmcnt-free)
    {
        int idx = threadIdx.x;
        if (idx < T - 1) sdt[idx] = tt[idx + 1] - tt[idx];
    }
    __syncthreads();   // one-time; waves independent afterwards

    const int lane = threadIdx.x & 63;
    const int q    = lane >> 4;          // quad
    const int c    = lane & 15;          // batch col in B/CD frags; row m in A frags
    const int wid  = threadIdx.x >> 6;
    const int wbase = blockIdx.x * (NW * MPW) + wid * MPW;   // 32 elems/wave

    const f32x4 zero4 = {0.0f, 0.0f, 0.0f, 0.0f};
    const unsigned biasdw = (q == 0) ? 0x3C00u : 0u;

    // Trans-free tanh (R3, unchanged -- numerics must stay identical):
    // odd poly x*P(x^2), deg-9, Chebyshev fit on |x|<=2, clamp via v_med3.
    const f32x2 tc0 = { 0.998805f,  0.998805f};
    const f32x2 tc1 = {-0.317916f, -0.317916f};
    const f32x2 tc2 = { 0.097206f,  0.097206f};
    const f32x2 tc3 = {-0.018404f, -0.018404f};
    const f32x2 tc4 = { 0.001476f,  0.001476f};

    auto tanh2 = [&](float a, float b) -> unsigned {
        f32x2 x;
        x[0] = __builtin_amdgcn_fmed3f(a, -2.0f, 2.0f);
        x[1] = __builtin_amdgcn_fmed3f(b, -2.0f, 2.0f);
        f32x2 s = x * x;
        f32x2 p = s * tc4 + tc3;
        p = p * s + tc2;
        p = p * s + tc1;
        p = p * s + tc0;
        p = p * x;
        return pkhf(p[0], p[1]);
    };

    // ---- persistent weight A-frags (f16; whole kernel; shared by streams) ----
    half8v A1o[4], A1d[4], A2o[2], A2d[2];
#pragma unroll
    for (int ti = 0; ti < 4; ti++) {
        A1o[ti] = afrag1(Wo1, bo1, LAT, ti, q, c, 1.0f);
        A1d[ti] = afrag1(Wd1, bd1, LAT, ti, q, c, 1.0f);
    }
#pragma unroll
    for (int ch = 0; ch < 2; ch++) {
        A2o[ch] = afrag2(Wo2, bo2, LAT, ch, q, c);
        A2d[ch] = afrag2(Wd2, bd2, 1, ch, q, c);
    }

    // ---- Encoder (transient f16 frags), one call per stream ----
    auto encode = [&](int base) -> f32x4 {
        uint4v bx = {0u, 0u, 0u, 0u};
        if (q == 0) {  // x at k=0,1; bias 1.0 at k=4
            bx[0] = pkhf(x0[2 * (base + c)], x0[2 * (base + c) + 1]);
            bx[2] = 0x3C00u;
        }
        half8v Bx = __builtin_bit_cast(half8v, bx);
        f32x4 h0 = MFMAH(afrag1(We1, be1, 2, 0, q, c, 1.0f), Bx, zero4);
        f32x4 h1 = MFMAH(afrag1(We1, be1, 2, 1, q, c, 1.0f), Bx, zero4);
        f32x4 h2 = MFMAH(afrag1(We1, be1, 2, 2, q, c, 1.0f), Bx, zero4);
        f32x4 h3 = MFMAH(afrag1(We1, be1, 2, 3, q, c, 1.0f), Bx, zero4);
        uint4v d0 = {pkhf(fmaxf(h0[0], 0.f), fmaxf(h0[1], 0.f)), pkhf(fmaxf(h0[2], 0.f), fmaxf(h0[3], 0.f)),
                     pkhf(fmaxf(h1[0], 0.f), fmaxf(h1[1], 0.f)), pkhf(fmaxf(h1[2], 0.f), fmaxf(h1[3], 0.f))};
        uint4v d1 = {pkhf(fmaxf(h2[0], 0.f), fmaxf(h2[1], 0.f)), pkhf(fmaxf(h2[2], 0.f), fmaxf(h2[3], 0.f)),
                     pkhf(fmaxf(h3[0], 0.f), fmaxf(h3[1], 0.f)), biasdw};
        return MFMAH(afrag2(We2, be2, 16, 1, q, c), __builtin_bit_cast(half8v, d1),
               MFMAH(afrag2(We2, be2, 16, 0, q, c), __builtin_bit_cast(half8v, d0), zero4));
    };
    f32x4 zA = encode(wbase);
    f32x4 zB = encode(wbase + 16);

    // z (CD layout) -> GEMM1 B-frag
    auto mkzfrag = [&](f32x4 zz) -> half8v {
        uint4v d = {pkhf(zz[0], zz[1]), pkhf(zz[2], zz[3]), biasdw, 0u};
        return __builtin_bit_cast(half8v, d);
    };

    // ODE func on BOTH streams, explicitly interleaved: all 8 layer-1 MFMAs
    // issue back-to-back (latencies overlap), then both poly blocks (pure
    // VALU, fills the MFMA shadow), then both layer-2 MFMA pairs.  R4: the
    // R3 counters showed 34% no-issue idle -- lockstep waves all stalling on
    // the same serial MFMA->poly->MFMA chain; a second independent stream in
    // the same wave converts that latency into issue slots.
    auto odef2 = [&](half8v zfA, half8v zfB, f32x4& kA, f32x4& kB) {
        f32x4 a0 = MFMAH(A1o[0], zfA, zero4);
        f32x4 a1 = MFMAH(A1o[1], zfA, zero4);
        f32x4 a2 = MFMAH(A1o[2], zfA, zero4);
        f32x4 a3 = MFMAH(A1o[3], zfA, zero4);
        f32x4 b0 = MFMAH(A1o[0], zfB, zero4);
        f32x4 b1 = MFMAH(A1o[1], zfB, zero4);
        f32x4 b2 = MFMAH(A1o[2], zfB, zero4);
        f32x4 b3 = MFMAH(A1o[3], zfB, zero4);
        uint4v da0 = {tanh2(a0[0], a0[1]), tanh2(a0[2], a0[3]),
                      tanh2(a1[0], a1[1]), tanh2(a1[2], a1[3])};
        uint4v da1 = {tanh2(a2[0], a2[1]), tanh2(a2[2], a2[3]),
                      tanh2(a3[0], a3[1]), biasdw};
        uint4v db0 = {tanh2(b0[0], b0[1]), tanh2(b0[2], b0[3]),
                      tanh2(b1[0], b1[1]), tanh2(b1[2], b1[3])};
        uint4v db1 = {tanh2(b2[0], b2[1]), tanh2(b2[2], b2[3]),
                      tanh2(b3[0], b3[1]), biasdw};
        kA = MFMAH(A2o[1], __builtin_bit_cast(half8v, da1),
             MFMAH(A2o[0], __builtin_bit_cast(half8v, da0), zero4));
        kB = MFMAH(A2o[1], __builtin_bit_cast(half8v, db1),
             MFMAH(A2o[0], __builtin_bit_cast(half8v, db0), zero4));
    };

    // decoder on both streams, same interleave; y in reg0 of q==0 lanes
    auto decode2 = [&](half8v zfA, half8v zfB, f32x4& yA, f32x4& yB) {
        f32x4 a0 = MFMAH(A1d[0], zfA, zero4);
        f32x4 a1 = MFMAH(A1d[1], zfA, zero4);
        f32x4 a2 = MFMAH(A1d[2], zfA, zero4);
        f32x4 a3 = MFMAH(A1d[3], zfA, zero4);
        f32x4 b0 = MFMAH(A1d[0], zfB, zero4);
        f32x4 b1 = MFMAH(A1d[1], zfB, zero4);
        f32x4 b2 = MFMAH(A1d[2], zfB, zero4);
        f32x4 b3 = MFMAH(A1d[3], zfB, zero4);
        uint4v da0 = {pkhf(fmaxf(a0[0], 0.f), fmaxf(a0[1], 0.f)), pkhf(fmaxf(a0[2], 0.f), fmaxf(a0[3], 0.f)),
                      pkhf(fmaxf(a1[0], 0.f), fmaxf(a1[1], 0.f)), pkhf(fmaxf(a1[2], 0.f), fmaxf(a1[3], 0.f))};
        uint4v da1 = {pkhf(fmaxf(a2[0], 0.f), fmaxf(a2[1], 0.f)), pkhf(fmaxf(a2[2], 0.f), fmaxf(a2[3], 0.f)),
                      pkhf(fmaxf(a3[0], 0.f), fmaxf(a3[1], 0.f)), biasdw};
        uint4v db0 = {pkhf(fmaxf(b0[0], 0.f), fmaxf(b0[1], 0.f)), pkhf(fmaxf(b0[2], 0.f), fmaxf(b0[3], 0.f)),
                      pkhf(fmaxf(b1[0], 0.f), fmaxf(b1[1], 0.f)), pkhf(fmaxf(b1[2], 0.f), fmaxf(b1[3], 0.f))};
        uint4v db1 = {pkhf(fmaxf(b2[0], 0.f), fmaxf(b2[1], 0.f)), pkhf(fmaxf(b2[2], 0.f), fmaxf(b2[3], 0.f)),
                      pkhf(fmaxf(b3[0], 0.f), fmaxf(b3[1], 0.f)), biasdw};
        yA = MFMAH(A2d[1], __builtin_bit_cast(half8v, da1),
             MFMAH(A2d[0], __builtin_bit_cast(half8v, da0), zero4));
        yB = MFMAH(A2d[1], __builtin_bit_cast(half8v, db1),
             MFMAH(A2d[0], __builtin_bit_cast(half8v, db0), zero4));
    };

    // ---- main time loop: register dataflow; only VMEM op is the out store ----
    for (int s = 0;; s++) {
        float dt = sdt[s];
        half8v zfA = mkzfrag(zA), zfB = mkzfrag(zB);
        f32x4 yA, yB;
        decode2(zfA, zfB, yA, yB);
        if (lane < 16) {
            out[(size_t)s * B + wbase + c]      = yA[0];
            out[(size_t)s * B + wbase + 16 + c] = yB[0];
        }

        if (s == T - 1) break;

        f32x4 kA, kB;
        odef2(zfA, zfB, kA, kB);                              // k1
        f32x4 ksA = kA, ksB = kB;
        f32x4 ztA = zA + (0.5f * dt) * kA;
        f32x4 ztB = zB + (0.5f * dt) * kB;
        odef2(mkzfrag(ztA), mkzfrag(ztB), kA, kB);            // k2
        ksA += 2.0f * kA; ksB += 2.0f * kB;
        ztA = zA + (0.5f * dt) * kA;
        ztB = zB + (0.5f * dt) * kB;
        odef2(mkzfrag(ztA), mkzfrag(ztB), kA, kB);            // k3
        ksA += 2.0f * kA; ksB += 2.0f * kB;
        ztA = zA + dt * kA;
        ztB = zB + dt * kB;
        odef2(mkzfrag(ztA), mkzfrag(ztB), kA, kB);            // k4
        zA = zA + (dt * (1.0f / 6.0f)) * (ksA + kA);
        zB = zB + (dt * (1.0f / 6.0f)) * (ksB + kB);
    }
}

extern "C" void kernel_launch(void* const* d_in, const int* in_sizes, int n_in,
                              void* d_out, int out_size, void* d_ws, size_t ws_size,
                              hipStream_t stream) {
    const float* x0  = (const float*)d_in[0];
    const float* t   = (const float*)d_in[1];
    const float* We1 = (const float*)d_in[2];
    const float* be1 = (const float*)d_in[3];
    const float* We2 = (const float*)d_in[4];
    const float* be2 = (const float*)d_in[5];
    const float* Wo1 = (const float*)d_in[6];
    const float* bo1 = (const float*)d_in[7];
    const float* Wo2 = (const float*)d_in[8];
    const float* bo2 = (const float*)d_in[9];
    const float* Wd1 = (const float*)d_in[10];
    const float* bd1 = (const float*)d_in[11];
    const float* Wd2 = (const float*)d_in[12];
    const float* bd2 = (const float*)d_in[13];
    float* out = (float*)d_out;

    int B = in_sizes[0] / 2;   // 65536
    int T = in_sizes[1];       // 100

    dim3 block(BLK);
    dim3 grid(B / (NW * MPW)); // 512 blocks, 4 waves x 2 M-tiles each
    hipLaunchKernelGGL(node_kernel, grid, block, 0, stream,
                       x0, t, We1, be1, We2, be2, Wo1, bo1, Wo2, bo2,
                       Wd1, bd1, Wd2, bd2, out, B, T);
}